// Round 1
// baseline (1010.836 us; speedup 1.0000x reference)
//
#include <hip/hip_runtime.h>
#include <stdint.h>

#define T_  4096
#define D_  1024
#define E_  8
#define F_  4096
#define H1_ 256
#define H2_ 64
#define SCALE_ 1.0f

typedef unsigned short ushort_t;
typedef unsigned int   uint32;
typedef __attribute__((ext_vector_type(8))) short  short8;
typedef __attribute__((ext_vector_type(4))) float  f32x4;
typedef __attribute__((ext_vector_type(4))) unsigned short us4;

__device__ __forceinline__ ushort_t f2bf(float f) {
  uint32 u = __float_as_uint(f);
  u += 0x7FFFu + ((u >> 16) & 1u);   // RNE
  return (ushort_t)(u >> 16);
}
__device__ __forceinline__ float bf2f(ushort_t u) {
  return __uint_as_float(((uint32)u) << 16);
}
// jax.nn.gelu default = tanh approximation
__device__ __forceinline__ float gelu_tanh(float x) {
  float u = 0.7978845608028654f * (x + 0.044715f * x * x * x);
  float e = __expf(2.0f * u);                 // tanh(u) = 1 - 2/(e^{2u}+1)
  return 0.5f * x * (1.0f + (1.0f - 2.0f / (e + 1.0f)));
}
__device__ __forceinline__ void gll16(const void* gptr, void* lptr) {
  void* g = const_cast<void*>(gptr);
  __builtin_amdgcn_global_load_lds((__attribute__((address_space(1))) void*)g,
                                   (__attribute__((address_space(3))) void*)lptr,
                                   16, 0, 0);
}

// ---------------- h -> bf16 ----------------
__global__ void k_cvt_h(const float* __restrict__ h, ushort_t* __restrict__ hb) {
  int i = (blockIdx.x * 256 + threadIdx.x) * 8;
  float4 a = *(const float4*)(h + i);
  float4 b = *(const float4*)(h + i + 4);
  short8 v;
  v[0] = (short)f2bf(a.x); v[1] = (short)f2bf(a.y);
  v[2] = (short)f2bf(a.z); v[3] = (short)f2bf(a.w);
  v[4] = (short)f2bf(b.x); v[5] = (short)f2bf(b.y);
  v[6] = (short)f2bf(b.z); v[7] = (short)f2bf(b.w);
  *(short8*)(hb + i) = v;
}

// ---------------- transpose + cvt: in [E][R][C] f32 -> out [E][C][R] bf16 ----
// reads: lane-strided column loads, line-reuse across 16 xi iterations (L1);
// writes: 64 lanes * ushort2 = 256B contiguous.
__global__ void k_transpose_bf16(const float* __restrict__ in, ushort_t* __restrict__ out,
                                 int R, int C) {
  const size_t per = (size_t)R * C;
  const float* src = in + per * blockIdx.z;
  ushort_t* dst = out + per * blockIdx.z;
  int lane = threadIdx.x & 63, wv = threadIdx.x >> 6;
  int r0 = blockIdx.x * 128 + lane * 2;
  int cB = blockIdx.y * 64 + wv * 16;
  for (int xi = 0; xi < 16; ++xi) {
    int c = cB + xi;
    float f0 = src[(size_t)r0 * C + c];
    float f1 = src[(size_t)(r0 + 1) * C + c];
    uint32 pack = (uint32)f2bf(f0) | ((uint32)f2bf(f1) << 16);
    *(uint32*)(dst + (size_t)c * R + r0) = pack;
  }
}

// ---------------- router layer1: g1 = relu(h@gw1+gb1), fp64 accumulate -------
__global__ void k_router1(const float* __restrict__ h, const float* __restrict__ gw1,
                          const float* __restrict__ gb1, float* __restrict__ g1) {
  __shared__ float sA[16][65];
  __shared__ float sB[16][65];
  int tx = threadIdx.x, ty = threadIdx.y;
  int tid = ty * 16 + tx;
  int m0 = blockIdx.y * 64, n0 = blockIdx.x * 64;
  double acc[4][4] = {};
  for (int k0 = 0; k0 < D_; k0 += 16) {
    {
      int m = tid & 63, kq = tid >> 6;
      float4 v = *(const float4*)(h + (size_t)(m0 + m) * D_ + k0 + kq * 4);
      sA[kq*4+0][m] = v.x; sA[kq*4+1][m] = v.y; sA[kq*4+2][m] = v.z; sA[kq*4+3][m] = v.w;
    }
    {
      int k = tid >> 4, nq = tid & 15;
      float4 v = *(const float4*)(gw1 + (size_t)(k0 + k) * H1_ + n0 + nq * 4);
      sB[k][nq*4+0] = v.x; sB[k][nq*4+1] = v.y; sB[k][nq*4+2] = v.z; sB[k][nq*4+3] = v.w;
    }
    __syncthreads();
#pragma unroll
    for (int k = 0; k < 16; ++k) {
      float a[4], b[4];
#pragma unroll
      for (int i = 0; i < 4; ++i) a[i] = sA[k][ty + i * 16];
#pragma unroll
      for (int j = 0; j < 4; ++j) b[j] = sB[k][tx * 4 + j];
#pragma unroll
      for (int i = 0; i < 4; ++i)
#pragma unroll
        for (int j = 0; j < 4; ++j)
          acc[i][j] += (double)a[i] * (double)b[j];
    }
    __syncthreads();
  }
  for (int i = 0; i < 4; ++i)
    for (int j = 0; j < 4; ++j) {
      int m = m0 + ty + i * 16, n = n0 + tx * 4 + j;
      float v = (float)acc[i][j] + gb1[n];
      g1[(size_t)m * H1_ + n] = fmaxf(v, 0.0f);
    }
}

// -------- router layers 2+3, logits out, top-2, counts (one wave per token) --
__global__ void k_router23(const float* __restrict__ g1, const float* __restrict__ gw2,
                           const float* __restrict__ gb2, const float* __restrict__ gw3,
                           float* __restrict__ logits_out, int* __restrict__ tokExp,
                           float* __restrict__ tokW, int* __restrict__ counts) {
  __shared__ float  sG1[4][256];
  __shared__ double sG2[4][64];
  __shared__ double sL[4][8];
  int lane = threadIdx.x & 63, wv = threadIdx.x >> 6;
  int t = blockIdx.x * 4 + wv;
  float4 v = *(const float4*)(g1 + (size_t)t * H1_ + lane * 4);
  sG1[wv][lane*4+0] = v.x; sG1[wv][lane*4+1] = v.y;
  sG1[wv][lane*4+2] = v.z; sG1[wv][lane*4+3] = v.w;
  __syncthreads();
  double acc = (double)gb2[lane];
  for (int k = 0; k < H1_; ++k)
    acc += (double)sG1[wv][k] * (double)gw2[k * H2_ + lane];
  sG2[wv][lane] = acc > 0.0 ? acc : 0.0;
  __syncthreads();
  if (lane < 8) {
    double l = 0.0;
    for (int j = 0; j < H2_; ++j) l += sG2[wv][j] * (double)gw3[j * E_ + lane];
    sL[wv][lane] = l;
    logits_out[(size_t)t * E_ + lane] = (float)l;
  }
  __syncthreads();
  if (lane == 0) {
    double best = -1e300, second = -1e300; int bi = 0, si = 0;
    for (int e = 0; e < E_; ++e) {
      double l = sL[wv][e];
      if (l > best)        { second = best; si = bi; best = l; bi = e; }
      else if (l > second) { second = l; si = e; }
    }
    double w0 = 1.0 / (1.0 + exp(second - best));  // softmax-top2 renormalized
    tokExp[t*2]   = bi; tokExp[t*2+1] = si;
    tokW[t*2]     = (float)w0;
    tokW[t*2+1]   = (float)(1.0 - w0);
    atomicAdd(&counts[bi], 1);
    atomicAdd(&counts[si], 1);
  }
}

__global__ void k_prefix(const int* __restrict__ counts, int* __restrict__ offsets,
                         int* __restrict__ cursor) {
  if (threadIdx.x == 0) {
    int s = 0;
    for (int e = 0; e < E_; ++e) { offsets[e] = s; s += counts[e]; cursor[e] = 0; }
  }
}

__global__ void k_assign(const int* __restrict__ tokExp, const float* __restrict__ tokW,
                         const int* __restrict__ offsets, int* cursor,
                         int* __restrict__ list, int* __restrict__ rowOf,
                         float* __restrict__ rowW) {
  int t = blockIdx.x * 256 + threadIdx.x;
  for (int k = 0; k < 2; ++k) {
    int e = tokExp[t*2+k];
    int pos = atomicAdd(&cursor[e], 1);
    int row = offsets[e] + pos;
    list[row] = t;
    rowOf[t*2+k] = row;
    rowW[row] = tokW[t*2+k];
  }
}

// ---------------- grouped GEMM pass1: act = gelu(gather(h) @ w1t^T + b1) -----
// 128x128 tile, BK=32, 4 waves (2x2), fragment-ordered LDS, global_load_lds x16B
__global__ __launch_bounds__(256) void k_moe_ffn1(
    const ushort_t* __restrict__ hb, const ushort_t* __restrict__ w1t,
    const float* __restrict__ b1, ushort_t* __restrict__ act,
    const int* __restrict__ list, const int* __restrict__ counts,
    const int* __restrict__ offsets) {
  int e = blockIdx.z;
  int cnt = counts[e];
  int mt = blockIdx.y;
  if (mt * 128 >= cnt) return;
  int off = offsets[e];
  int rowStart = off + mt * 128;
  int nBase = blockIdx.x * 128;
  const ushort_t* B = w1t + (size_t)e * F_ * D_;   // [F_][D_] n-major, k-contig
  int tid = threadIdx.x, w = tid >> 6, lane = tid & 63;
  int m16 = lane & 15, kq = lane >> 4;
  __shared__ short8 lA[512];   // [rowtile 0..7][slot = kq*16+m]
  __shared__ short8 lB[512];   // [coltile 0..7][slot = kq*16+n]
  int gr0 = rowStart + (w * 2) * 16 + m16;
  int gr1 = gr0 + 16;
  int t0 = list[min(gr0, 2 * T_ - 1)];
  int t1 = list[min(gr1, 2 * T_ - 1)];
  const ushort_t* aS0 = hb + (size_t)t0 * D_ + kq * 8;
  const ushort_t* aS1 = hb + (size_t)t1 * D_ + kq * 8;
  const ushort_t* bS0 = B + (size_t)(nBase + (w * 2) * 16 + m16) * D_ + kq * 8;
  const ushort_t* bS1 = bS0 + (size_t)16 * D_;
  short8* dA0 = &lA[(w * 2) * 64];
  short8* dA1 = &lA[(w * 2 + 1) * 64];
  short8* dB0 = &lB[(w * 2) * 64];
  short8* dB1 = &lB[(w * 2 + 1) * 64];
  int wr = w >> 1, wc = w & 1;
  f32x4 acc[4][4] = {};
  for (int k0 = 0; k0 < D_; k0 += 32) {
    gll16(aS0 + k0, dA0);
    gll16(aS1 + k0, dA1);
    gll16(bS0 + k0, dB0);
    gll16(bS1 + k0, dB1);
    __syncthreads();
    short8 af[4], bf[4];
#pragma unroll
    for (int i = 0; i < 4; ++i) af[i] = lA[(wr * 4 + i) * 64 + lane];
#pragma unroll
    for (int j = 0; j < 4; ++j) bf[j] = lB[(wc * 4 + j) * 64 + lane];
#pragma unroll
    for (int i = 0; i < 4; ++i)
#pragma unroll
      for (int j = 0; j < 4; ++j)
        acc[i][j] = __builtin_amdgcn_mfma_f32_16x16x32_bf16(af[i], bf[j], acc[i][j], 0, 0, 0);
    __syncthreads();
  }
  const float* b1e = b1 + (size_t)e * F_;
  int quad = lane >> 4, cn = lane & 15;
#pragma unroll
  for (int i = 0; i < 4; ++i) {
    int lrow = (wr * 4 + i) * 16 + quad * 4;
#pragma unroll
    for (int r = 0; r < 4; ++r) {
      int slot = mt * 128 + lrow + r;
      if (slot < cnt) {
        size_t gr = (size_t)off + slot;
#pragma unroll
        for (int j = 0; j < 4; ++j) {
          int n = nBase + (wc * 4 + j) * 16 + cn;
          float x = acc[i][j][r] + b1e[n];
          act[gr * F_ + n] = f2bf(gelu_tanh(x));
        }
      }
    }
  }
}

// ---------------- grouped GEMM pass2: ybuf = (act @ w2t^T + b2) * w * SCALE --
__global__ __launch_bounds__(256) void k_moe_ffn2(
    const ushort_t* __restrict__ act, const ushort_t* __restrict__ w2t,
    const float* __restrict__ b2, const float* __restrict__ rowW,
    ushort_t* __restrict__ ybuf, const int* __restrict__ counts,
    const int* __restrict__ offsets) {
  int e = blockIdx.z;
  int cnt = counts[e];
  int mt = blockIdx.y;
  if (mt * 128 >= cnt) return;
  int off = offsets[e];
  int rowStart = off + mt * 128;
  int nBase = blockIdx.x * 128;
  const ushort_t* B = w2t + (size_t)e * D_ * F_;   // [D_][F_] n-major, k-contig
  int tid = threadIdx.x, w = tid >> 6, lane = tid & 63;
  int m16 = lane & 15, kq = lane >> 4;
  __shared__ short8 lA[512];
  __shared__ short8 lB[512];
  int gr0 = rowStart + (w * 2) * 16 + m16;
  int gr1 = gr0 + 16;
  const ushort_t* aS0 = act + (size_t)min(gr0, 2 * T_ - 1) * F_ + kq * 8;
  const ushort_t* aS1 = act + (size_t)min(gr1, 2 * T_ - 1) * F_ + kq * 8;
  const ushort_t* bS0 = B + (size_t)(nBase + (w * 2) * 16 + m16) * F_ + kq * 8;
  const ushort_t* bS1 = bS0 + (size_t)16 * F_;
  short8* dA0 = &lA[(w * 2) * 64];
  short8* dA1 = &lA[(w * 2 + 1) * 64];
  short8* dB0 = &lB[(w * 2) * 64];
  short8* dB1 = &lB[(w * 2 + 1) * 64];
  int wr = w >> 1, wc = w & 1;
  f32x4 acc[4][4] = {};
  for (int k0 = 0; k0 < F_; k0 += 32) {
    gll16(aS0 + k0, dA0);
    gll16(aS1 + k0, dA1);
    gll16(bS0 + k0, dB0);
    gll16(bS1 + k0, dB1);
    __syncthreads();
    short8 af[4], bf[4];
#pragma unroll
    for (int i = 0; i < 4; ++i) af[i] = lA[(wr * 4 + i) * 64 + lane];
#pragma unroll
    for (int j = 0; j < 4; ++j) bf[j] = lB[(wc * 4 + j) * 64 + lane];
#pragma unroll
    for (int i = 0; i < 4; ++i)
#pragma unroll
      for (int j = 0; j < 4; ++j)
        acc[i][j] = __builtin_amdgcn_mfma_f32_16x16x32_bf16(af[i], bf[j], acc[i][j], 0, 0, 0);
    __syncthreads();
  }
  const float* b2e = b2 + (size_t)e * D_;
  int quad = lane >> 4, cn = lane & 15;
#pragma unroll
  for (int i = 0; i < 4; ++i) {
    int lrow = (wr * 4 + i) * 16 + quad * 4;
#pragma unroll
    for (int r = 0; r < 4; ++r) {
      int slot = mt * 128 + lrow + r;
      if (slot < cnt) {
        size_t gr = (size_t)off + slot;
        float wgt = rowW[gr] * SCALE_;
#pragma unroll
        for (int j = 0; j < 4; ++j) {
          int n = nBase + (wc * 4 + j) * 16 + cn;
          float x = (acc[i][j][r] + b2e[n]) * wgt;
          ybuf[gr * D_ + n] = f2bf(x);
        }
      }
    }
  }
}

// ---------------- combine: out[t] = ybuf[rowA] + ybuf[rowB] ------------------
__global__ void k_combine(const ushort_t* __restrict__ ybuf, const int* __restrict__ rowOf,
                          float* __restrict__ out) {
  int t = blockIdx.x;
  int rA = rowOf[t*2], rB = rowOf[t*2+1];
  int d = threadIdx.x * 4;
  us4 a = *(const us4*)(ybuf + (size_t)rA * D_ + d);
  us4 b = *(const us4*)(ybuf + (size_t)rB * D_ + d);
  float4 o;
  o.x = bf2f(a[0]) + bf2f(b[0]);
  o.y = bf2f(a[1]) + bf2f(b[1]);
  o.z = bf2f(a[2]) + bf2f(b[2]);
  o.w = bf2f(a[3]) + bf2f(b[3]);
  *(float4*)(out + (size_t)t * D_ + d) = o;
}

extern "C" void kernel_launch(void* const* d_in, const int* in_sizes, int n_in,
                              void* d_out, int out_size, void* d_ws, size_t ws_size,
                              hipStream_t stream) {
  const float* h   = (const float*)d_in[0];
  const float* gw1 = (const float*)d_in[1];
  const float* gb1 = (const float*)d_in[2];
  const float* gw2 = (const float*)d_in[3];
  const float* gb2 = (const float*)d_in[4];
  const float* gw3 = (const float*)d_in[5];
  const float* w1  = (const float*)d_in[6];
  const float* b1  = (const float*)d_in[7];
  const float* w2  = (const float*)d_in[8];
  const float* b2  = (const float*)d_in[9];
  float* out    = (float*)d_out;
  float* logits = out + (size_t)T_ * D_;

  char* ws = (char*)d_ws;
  size_t o = 0;
  auto alloc = [&](size_t bytes) -> void* {
    o = (o + 255) & ~(size_t)255;
    void* p = ws + o;
    o += bytes;
    return p;
  };
  int*      counts  = (int*)alloc(E_ * 4);
  int*      cursor  = (int*)alloc(E_ * 4);
  int*      offsets = (int*)alloc(E_ * 4);
  int*      tokExp  = (int*)alloc((size_t)T_ * 2 * 4);
  float*    tokW    = (float*)alloc((size_t)T_ * 2 * 4);
  int*      list    = (int*)alloc((size_t)2 * T_ * 4);
  int*      rowOf   = (int*)alloc((size_t)2 * T_ * 4);
  float*    rowW    = (float*)alloc((size_t)2 * T_ * 4);
  float*    g1      = (float*)alloc((size_t)T_ * H1_ * 4);
  ushort_t* hb      = (ushort_t*)alloc((size_t)T_ * D_ * 2);
  ushort_t* w1t     = (ushort_t*)alloc((size_t)E_ * D_ * F_ * 2);
  ushort_t* w2t     = (ushort_t*)alloc((size_t)E_ * D_ * F_ * 2);
  ushort_t* act     = (ushort_t*)alloc((size_t)2 * T_ * F_ * 2);
  ushort_t* ybuf    = (ushort_t*)alloc((size_t)2 * T_ * D_ * 2);
  (void)ws_size; (void)in_sizes; (void)n_in; (void)out_size;

  hipMemsetAsync(counts, 0, E_ * 4, stream);
  k_cvt_h<<<T_ * D_ / 2048, 256, 0, stream>>>(h, hb);
  k_transpose_bf16<<<dim3(D_ / 128, F_ / 64, E_), 256, 0, stream>>>(w1, w1t, D_, F_);
  k_transpose_bf16<<<dim3(F_ / 128, D_ / 64, E_), 256, 0, stream>>>(w2, w2t, F_, D_);
  k_router1<<<dim3(H1_ / 64, T_ / 64), dim3(16, 16), 0, stream>>>(h, gw1, gb1, g1);
  k_router23<<<T_ / 4, 256, 0, stream>>>(g1, gw2, gb2, gw3, logits, tokExp, tokW, counts);
  k_prefix<<<1, 64, 0, stream>>>(counts, offsets, cursor);
  k_assign<<<T_ / 256, 256, 0, stream>>>(tokExp, tokW, offsets, cursor, list, rowOf, rowW);
  k_moe_ffn1<<<dim3(F_ / 128, T_ / 128, E_), 256, 0, stream>>>(hb, w1t, b1, act, list, counts, offsets);
  k_moe_ffn2<<<dim3(D_ / 128, T_ / 128, E_), 256, 0, stream>>>(act, w2t, b2, rowW, ybuf, counts, offsets);
  k_combine<<<T_, 256, 0, stream>>>(ybuf, rowOf, out);
}

// Round 2
// 979.941 us; speedup vs baseline: 1.0315x; 1.0315x over previous
//
#include <hip/hip_runtime.h>
#include <stdint.h>

#define T_  4096
#define D_  1024
#define E_  8
#define F_  4096
#define H1_ 256
#define H2_ 64
#define SCALE_ 1.0f

typedef unsigned short ushort_t;
typedef unsigned int   uint32;
typedef __attribute__((ext_vector_type(8))) short  short8;
typedef __attribute__((ext_vector_type(4))) float  f32x4;
typedef __attribute__((ext_vector_type(4))) unsigned short us4;
typedef __attribute__((ext_vector_type(8))) unsigned short us8;

__device__ __forceinline__ ushort_t f2bf(float f) {
  uint32 u = __float_as_uint(f);
  u += 0x7FFFu + ((u >> 16) & 1u);   // RNE
  return (ushort_t)(u >> 16);
}
__device__ __forceinline__ float bf2f(ushort_t u) {
  return __uint_as_float(((uint32)u) << 16);
}
// jax.nn.gelu default = tanh approximation
__device__ __forceinline__ float gelu_tanh(float x) {
  float u = 0.7978845608028654f * (x + 0.044715f * x * x * x);
  float e = __expf(2.0f * u);
  return 0.5f * x * (1.0f + (1.0f - 2.0f / (e + 1.0f)));
}
__device__ __forceinline__ void gll16(const void* gptr, void* lptr) {
  void* g = const_cast<void*>(gptr);
  __builtin_amdgcn_global_load_lds((__attribute__((address_space(1))) void*)g,
                                   (__attribute__((address_space(3))) void*)lptr,
                                   16, 0, 0);
}

// ---------------- h -> bf16 ----------------
__global__ void k_cvt_h(const float* __restrict__ h, ushort_t* __restrict__ hb) {
  int i = (blockIdx.x * 256 + threadIdx.x) * 8;
  float4 a = *(const float4*)(h + i);
  float4 b = *(const float4*)(h + i + 4);
  short8 v;
  v[0] = (short)f2bf(a.x); v[1] = (short)f2bf(a.y);
  v[2] = (short)f2bf(a.z); v[3] = (short)f2bf(a.w);
  v[4] = (short)f2bf(b.x); v[5] = (short)f2bf(b.y);
  v[6] = (short)f2bf(b.z); v[7] = (short)f2bf(b.w);
  *(short8*)(hb + i) = v;
}

// ---- transpose + cvt: in [E][R][C] f32 -> out [E][C][R] bf16, LDS-tiled ----
// Phase1: coalesced float4 reads, row-major LDS (pad 65 -> conflict-free col reads)
// Phase2: conflict-free scalar column reads, 2x16B coalesced bf16 stores.
__global__ void k_transpose_bf16(const float* __restrict__ in, ushort_t* __restrict__ out,
                                 int R, int C) {
  __shared__ float ltf[64][65];
  const size_t per = (size_t)R * C;
  const float* src = in + per * blockIdx.z;
  ushort_t* dst = out + per * blockIdx.z;
  int r0 = blockIdx.x * 64, c0 = blockIdx.y * 64;
  int tid = threadIdx.x;
  int cg = (tid & 15) * 4;
  int rr = tid >> 4;
#pragma unroll
  for (int rb = 0; rb < 64; rb += 16) {
    int r = rb + rr;
    float4 v = *(const float4*)(src + (size_t)(r0 + r) * C + c0 + cg);
    ltf[r][cg + 0] = v.x; ltf[r][cg + 1] = v.y;
    ltf[r][cg + 2] = v.z; ltf[r][cg + 3] = v.w;
  }
  __syncthreads();
  int c = tid >> 2, rch = (tid & 3) * 16;
  ushort_t tmp[16];
#pragma unroll
  for (int i = 0; i < 16; ++i) tmp[i] = f2bf(ltf[rch + i][c]);
  ushort_t* dp = dst + (size_t)(c0 + c) * R + r0 + rch;
  *(us8*)dp = *(const us8*)&tmp[0];
  *(us8*)(dp + 8) = *(const us8*)&tmp[8];
}

// ------- router layer1 split-K: p1[kc] = h[:, kc*256:+256] @ gw1 chunk, f64 --
__global__ void k_router1(const float* __restrict__ h, const float* __restrict__ gw1,
                          double* __restrict__ p1) {
  __shared__ float sA[16][65];
  __shared__ float sB[16][65];
  int tx = threadIdx.x, ty = threadIdx.y;
  int tid = ty * 16 + tx;
  int m0 = blockIdx.y * 64, n0 = blockIdx.x * 64;
  int kc = blockIdx.z;
  double acc[4][4] = {};
  for (int k0 = kc * 256; k0 < kc * 256 + 256; k0 += 16) {
    {
      int m = tid & 63, kq = tid >> 6;
      float4 v = *(const float4*)(h + (size_t)(m0 + m) * D_ + k0 + kq * 4);
      sA[kq*4+0][m] = v.x; sA[kq*4+1][m] = v.y; sA[kq*4+2][m] = v.z; sA[kq*4+3][m] = v.w;
    }
    {
      int k = tid >> 4, nq = tid & 15;
      float4 v = *(const float4*)(gw1 + (size_t)(k0 + k) * H1_ + n0 + nq * 4);
      sB[k][nq*4+0] = v.x; sB[k][nq*4+1] = v.y; sB[k][nq*4+2] = v.z; sB[k][nq*4+3] = v.w;
    }
    __syncthreads();
#pragma unroll
    for (int k = 0; k < 16; ++k) {
      float a[4], b[4];
#pragma unroll
      for (int i = 0; i < 4; ++i) a[i] = sA[k][ty + i * 16];
#pragma unroll
      for (int j = 0; j < 4; ++j) b[j] = sB[k][tx * 4 + j];
#pragma unroll
      for (int i = 0; i < 4; ++i)
#pragma unroll
        for (int j = 0; j < 4; ++j)
          acc[i][j] += (double)a[i] * (double)b[j];
    }
    __syncthreads();
  }
  double* pd = p1 + (size_t)kc * T_ * H1_;
  for (int i = 0; i < 4; ++i)
    for (int j = 0; j < 4; ++j) {
      int m = m0 + ty + i * 16, n = n0 + tx * 4 + j;
      pd[(size_t)m * H1_ + n] = acc[i][j];
    }
}

__global__ void k_router1_reduce(const double* __restrict__ p1, const float* __restrict__ gb1,
                                 double* __restrict__ g1) {
  int i = blockIdx.x * 256 + threadIdx.x;
  const size_t TH = (size_t)T_ * H1_;
  double s = p1[i] + p1[i + TH] + p1[i + 2 * TH] + p1[i + 3 * TH] + (double)gb1[i & (H1_ - 1)];
  g1[i] = s > 0.0 ? s : 0.0;
}

// -------- router layers 2+3, logits out, top-2, counts (one wave per token) --
__global__ void k_router23(const double* __restrict__ g1, const float* __restrict__ gw2,
                           const float* __restrict__ gb2, const float* __restrict__ gw3,
                           float* __restrict__ logits_out, int* __restrict__ tokExp,
                           float* __restrict__ tokW, int* __restrict__ counts) {
  __shared__ double sG1[4][256];
  __shared__ double sG2[4][64];
  __shared__ double sL[4][8];
  int lane = threadIdx.x & 63, wv = threadIdx.x >> 6;
  int t = blockIdx.x * 4 + wv;
  const double* gp = g1 + (size_t)t * H1_ + lane * 4;
  double2 va = *(const double2*)gp;
  double2 vb = *(const double2*)(gp + 2);
  sG1[wv][lane*4+0] = va.x; sG1[wv][lane*4+1] = va.y;
  sG1[wv][lane*4+2] = vb.x; sG1[wv][lane*4+3] = vb.y;
  __syncthreads();
  double acc = (double)gb2[lane];
  for (int k = 0; k < H1_; ++k)
    acc += sG1[wv][k] * (double)gw2[k * H2_ + lane];
  sG2[wv][lane] = acc > 0.0 ? acc : 0.0;
  __syncthreads();
  if (lane < 8) {
    double l = 0.0;
    for (int j = 0; j < H2_; ++j) l += sG2[wv][j] * (double)gw3[j * E_ + lane];
    sL[wv][lane] = l;
    logits_out[(size_t)t * E_ + lane] = (float)l;
  }
  __syncthreads();
  if (lane == 0) {
    double best = -1e300, second = -1e300; int bi = 0, si = 0;
    for (int e = 0; e < E_; ++e) {
      double l = sL[wv][e];
      if (l > best)        { second = best; si = bi; best = l; bi = e; }
      else if (l > second) { second = l; si = e; }
    }
    double w0 = 1.0 / (1.0 + exp(second - best));
    tokExp[t*2]   = bi; tokExp[t*2+1] = si;
    tokW[t*2]     = (float)w0;
    tokW[t*2+1]   = (float)(1.0 - w0);
    atomicAdd(&counts[bi], 1);
    atomicAdd(&counts[si], 1);
  }
}

__global__ void k_prefix(const int* __restrict__ counts, int* __restrict__ offsets,
                         int* __restrict__ cursor) {
  if (threadIdx.x == 0) {
    int s = 0;
    for (int e = 0; e < E_; ++e) { offsets[e] = s; s += counts[e]; cursor[e] = 0; }
  }
}

__global__ void k_assign(const int* __restrict__ tokExp, const float* __restrict__ tokW,
                         const int* __restrict__ offsets, int* cursor,
                         int* __restrict__ list, int* __restrict__ rowOf,
                         float* __restrict__ rowW) {
  int t = blockIdx.x * 256 + threadIdx.x;
  for (int k = 0; k < 2; ++k) {
    int e = tokExp[t*2+k];
    int pos = atomicAdd(&cursor[e], 1);
    int row = offsets[e] + pos;
    list[row] = t;
    rowOf[t*2+k] = row;
    rowW[row] = tokW[t*2+k];
  }
}

// -------- grouped GEMM pass1: act = gelu(gather(h) @ w1t^T + b1) -------------
// 128x128 tile, BK=32, double-buffered LDS, ONE barrier per K-step.
__global__ __launch_bounds__(256) void k_moe_ffn1(
    const ushort_t* __restrict__ hb, const ushort_t* __restrict__ w1t,
    const float* __restrict__ b1, ushort_t* __restrict__ act,
    const int* __restrict__ list, const int* __restrict__ counts,
    const int* __restrict__ offsets) {
  int e = blockIdx.z;
  int cnt = counts[e];
  int mt = blockIdx.y;
  if (mt * 128 >= cnt) return;
  int off = offsets[e];
  int rowStart = off + mt * 128;
  int nBase = blockIdx.x * 128;
  const ushort_t* B = w1t + (size_t)e * F_ * D_;
  int tid = threadIdx.x, w = tid >> 6, lane = tid & 63;
  int m16 = lane & 15, kq = lane >> 4;
  __shared__ short8 lA[2][512];
  __shared__ short8 lB[2][512];
  int gr0 = rowStart + (w * 2) * 16 + m16;
  int gr1 = gr0 + 16;
  int t0 = list[min(gr0, 2 * T_ - 1)];
  int t1 = list[min(gr1, 2 * T_ - 1)];
  const ushort_t* aS0 = hb + (size_t)t0 * D_ + kq * 8;
  const ushort_t* aS1 = hb + (size_t)t1 * D_ + kq * 8;
  const ushort_t* bS0 = B + (size_t)(nBase + (w * 2) * 16 + m16) * D_ + kq * 8;
  const ushort_t* bS1 = bS0 + (size_t)16 * D_;
  int wr = w >> 1, wc = w & 1;
  f32x4 acc[4][4] = {};
  // prologue: stage k0=0 into buf0
  gll16(aS0, &lA[0][(w * 2) * 64]);
  gll16(aS1, &lA[0][(w * 2 + 1) * 64]);
  gll16(bS0, &lB[0][(w * 2) * 64]);
  gll16(bS1, &lB[0][(w * 2 + 1) * 64]);
  for (int s = 0; s < D_ / 32; ++s) {
    __syncthreads();                     // buf p loads complete; prior reads drained
    int p = s & 1;
    int kn = (s + 1) * 32;
    if (kn < D_) {
      int q = p ^ 1;
      gll16(aS0 + kn, &lA[q][(w * 2) * 64]);
      gll16(aS1 + kn, &lA[q][(w * 2 + 1) * 64]);
      gll16(bS0 + kn, &lB[q][(w * 2) * 64]);
      gll16(bS1 + kn, &lB[q][(w * 2 + 1) * 64]);
    }
    short8 af[4], bf4[4];
#pragma unroll
    for (int i = 0; i < 4; ++i) af[i] = lA[p][(wr * 4 + i) * 64 + lane];
#pragma unroll
    for (int j = 0; j < 4; ++j) bf4[j] = lB[p][(wc * 4 + j) * 64 + lane];
#pragma unroll
    for (int i = 0; i < 4; ++i)
#pragma unroll
      for (int j = 0; j < 4; ++j)
        acc[i][j] = __builtin_amdgcn_mfma_f32_16x16x32_bf16(af[i], bf4[j], acc[i][j], 0, 0, 0);
  }
  const float* b1e = b1 + (size_t)e * F_;
  int quad = lane >> 4, cn = lane & 15;
#pragma unroll
  for (int i = 0; i < 4; ++i) {
    int lrow = (wr * 4 + i) * 16 + quad * 4;
#pragma unroll
    for (int r = 0; r < 4; ++r) {
      int slot = mt * 128 + lrow + r;
      if (slot < cnt) {
        size_t gr = (size_t)off + slot;
#pragma unroll
        for (int j = 0; j < 4; ++j) {
          int n = nBase + (wc * 4 + j) * 16 + cn;
          float x = acc[i][j][r] + b1e[n];
          act[gr * F_ + n] = f2bf(gelu_tanh(x));
        }
      }
    }
  }
}

// -------- grouped GEMM pass2: ybuf = (act @ w2t^T + b2) * w * SCALE ----------
// 64x128 tile (2x parallelism vs 128-tile), BK=32, double-buffered, 1 barrier.
__global__ __launch_bounds__(256) void k_moe_ffn2(
    const ushort_t* __restrict__ act, const ushort_t* __restrict__ w2t,
    const float* __restrict__ b2, const float* __restrict__ rowW,
    ushort_t* __restrict__ ybuf, const int* __restrict__ counts,
    const int* __restrict__ offsets) {
  int e = blockIdx.z;
  int cnt = counts[e];
  int mt = blockIdx.y;
  if (mt * 64 >= cnt) return;
  int off = offsets[e];
  int rowStart = off + mt * 64;
  int nBase = blockIdx.x * 128;
  const ushort_t* B = w2t + (size_t)e * D_ * F_;
  int tid = threadIdx.x, w = tid >> 6, lane = tid & 63;
  int m16 = lane & 15, kq = lane >> 4;
  __shared__ short8 lA[2][256];
  __shared__ short8 lB[2][512];
  int gr = rowStart + w * 16 + m16;
  const ushort_t* aS = act + (size_t)min(gr, 2 * T_ - 1) * F_ + kq * 8;
  const ushort_t* bS0 = B + (size_t)(nBase + w * 32 + m16) * F_ + kq * 8;
  const ushort_t* bS1 = bS0 + (size_t)16 * F_;
  int wr = w >> 1, wc = w & 1;
  f32x4 acc[2][4] = {};
  gll16(aS, &lA[0][w * 64]);
  gll16(bS0, &lB[0][(w * 2) * 64]);
  gll16(bS1, &lB[0][(w * 2 + 1) * 64]);
  for (int s = 0; s < F_ / 32; ++s) {
    __syncthreads();
    int p = s & 1;
    int kn = (s + 1) * 32;
    if (kn < F_) {
      int q = p ^ 1;
      gll16(aS + kn, &lA[q][w * 64]);
      gll16(bS0 + kn, &lB[q][(w * 2) * 64]);
      gll16(bS1 + kn, &lB[q][(w * 2 + 1) * 64]);
    }
    short8 af[2], bf4[4];
#pragma unroll
    for (int i = 0; i < 2; ++i) af[i] = lA[p][(wr * 2 + i) * 64 + lane];
#pragma unroll
    for (int j = 0; j < 4; ++j) bf4[j] = lB[p][(wc * 4 + j) * 64 + lane];
#pragma unroll
    for (int i = 0; i < 2; ++i)
#pragma unroll
      for (int j = 0; j < 4; ++j)
        acc[i][j] = __builtin_amdgcn_mfma_f32_16x16x32_bf16(af[i], bf4[j], acc[i][j], 0, 0, 0);
  }
  const float* b2e = b2 + (size_t)e * D_;
  int quad = lane >> 4, cn = lane & 15;
#pragma unroll
  for (int i = 0; i < 2; ++i) {
    int lrow = (wr * 2 + i) * 16 + quad * 4;
#pragma unroll
    for (int r = 0; r < 4; ++r) {
      int slot = mt * 64 + lrow + r;
      if (slot < cnt) {
        size_t g = (size_t)off + slot;
        float wgt = rowW[g] * SCALE_;
#pragma unroll
        for (int j = 0; j < 4; ++j) {
          int n = nBase + (wc * 4 + j) * 16 + cn;
          float x = (acc[i][j][r] + b2e[n]) * wgt;
          ybuf[g * D_ + n] = f2bf(x);
        }
      }
    }
  }
}

// ---------------- combine: out[t] = ybuf[rowA] + ybuf[rowB] ------------------
__global__ void k_combine(const ushort_t* __restrict__ ybuf, const int* __restrict__ rowOf,
                          float* __restrict__ out) {
  int t = blockIdx.x;
  int rA = rowOf[t*2], rB = rowOf[t*2+1];
  int d = threadIdx.x * 4;
  us4 a = *(const us4*)(ybuf + (size_t)rA * D_ + d);
  us4 b = *(const us4*)(ybuf + (size_t)rB * D_ + d);
  float4 o;
  o.x = bf2f(a[0]) + bf2f(b[0]);
  o.y = bf2f(a[1]) + bf2f(b[1]);
  o.z = bf2f(a[2]) + bf2f(b[2]);
  o.w = bf2f(a[3]) + bf2f(b[3]);
  *(float4*)(out + (size_t)t * D_ + d) = o;
}

extern "C" void kernel_launch(void* const* d_in, const int* in_sizes, int n_in,
                              void* d_out, int out_size, void* d_ws, size_t ws_size,
                              hipStream_t stream) {
  const float* h   = (const float*)d_in[0];
  const float* gw1 = (const float*)d_in[1];
  const float* gb1 = (const float*)d_in[2];
  const float* gw2 = (const float*)d_in[3];
  const float* gb2 = (const float*)d_in[4];
  const float* gw3 = (const float*)d_in[5];
  const float* w1  = (const float*)d_in[6];
  const float* b1  = (const float*)d_in[7];
  const float* w2  = (const float*)d_in[8];
  const float* b2  = (const float*)d_in[9];
  float* out    = (float*)d_out;
  float* logits = out + (size_t)T_ * D_;

  char* ws = (char*)d_ws;
  size_t o = 0;
  auto alloc = [&](size_t bytes) -> void* {
    o = (o + 255) & ~(size_t)255;
    void* p = ws + o;
    o += bytes;
    return p;
  };
  int*      counts  = (int*)alloc(E_ * 4);
  int*      cursor  = (int*)alloc(E_ * 4);
  int*      offsets = (int*)alloc(E_ * 4);
  int*      tokExp  = (int*)alloc((size_t)T_ * 2 * 4);
  float*    tokW    = (float*)alloc((size_t)T_ * 2 * 4);
  int*      list    = (int*)alloc((size_t)2 * T_ * 4);
  int*      rowOf   = (int*)alloc((size_t)2 * T_ * 4);
  float*    rowW    = (float*)alloc((size_t)2 * T_ * 4);
  double*   g1      = (double*)alloc((size_t)T_ * H1_ * 8);
  ushort_t* hb      = (ushort_t*)alloc((size_t)T_ * D_ * 2);
  ushort_t* w1t     = (ushort_t*)alloc((size_t)E_ * D_ * F_ * 2);
  ushort_t* w2t     = (ushort_t*)alloc((size_t)E_ * D_ * F_ * 2);
  // big region: p1 (32 MB, dead after k_router1_reduce) aliases act/ybuf (80 MB)
  char*     big     = (char*)alloc((size_t)2 * T_ * F_ * 2 + (size_t)2 * T_ * D_ * 2);
  double*   p1      = (double*)big;                                  // [4][T][H1] f64 = 32 MB
  ushort_t* act     = (ushort_t*)big;                                // [2T][F] bf16 = 64 MB
  ushort_t* ybuf    = (ushort_t*)(big + (size_t)2 * T_ * F_ * 2);    // [2T][D] bf16 = 16 MB
  (void)ws_size; (void)in_sizes; (void)n_in; (void)out_size;

  hipMemsetAsync(counts, 0, E_ * 4, stream);
  k_cvt_h<<<T_ * D_ / 2048, 256, 0, stream>>>(h, hb);
  k_transpose_bf16<<<dim3(D_ / 64, F_ / 64, E_), 256, 0, stream>>>(w1, w1t, D_, F_);
  k_transpose_bf16<<<dim3(F_ / 64, D_ / 64, E_), 256, 0, stream>>>(w2, w2t, F_, D_);
  k_router1<<<dim3(H1_ / 64, T_ / 64, 4), dim3(16, 16), 0, stream>>>(h, gw1, p1);
  k_router1_reduce<<<T_ * H1_ / 256, 256, 0, stream>>>(p1, gb1, g1);
  k_router23<<<T_ / 4, 256, 0, stream>>>(g1, gw2, gb2, gw3, logits, tokExp, tokW, counts);
  k_prefix<<<1, 64, 0, stream>>>(counts, offsets, cursor);
  k_assign<<<T_ / 256, 256, 0, stream>>>(tokExp, tokW, offsets, cursor, list, rowOf, rowW);
  k_moe_ffn1<<<dim3(F_ / 128, T_ / 128, E_), 256, 0, stream>>>(hb, w1t, b1, act, list, counts, offsets);
  k_moe_ffn2<<<dim3(D_ / 128, T_ * 2 / 64, E_), 256, 0, stream>>>(act, w2t, b2, rowW, ybuf, counts, offsets);
  k_combine<<<T_, 256, 0, stream>>>(ybuf, rowOf, out);
}

// Round 3
// 934.167 us; speedup vs baseline: 1.0821x; 1.0490x over previous
//
#include <hip/hip_runtime.h>
#include <stdint.h>

#define T_  4096
#define D_  1024
#define E_  8
#define F_  4096
#define H1_ 256
#define H2_ 64
#define SCALE_ 1.0f
#define NROW_ (2 * T_)

typedef unsigned short ushort_t;
typedef unsigned int   uint32;
typedef __attribute__((ext_vector_type(8))) short  short8;
typedef __attribute__((ext_vector_type(4))) float  f32x4;
typedef __attribute__((ext_vector_type(8))) unsigned short us8;

__device__ __forceinline__ ushort_t f2bf(float f) {
  uint32 u = __float_as_uint(f);
  u += 0x7FFFu + ((u >> 16) & 1u);   // RNE
  return (ushort_t)(u >> 16);
}
// jax.nn.gelu default = tanh approximation
__device__ __forceinline__ float gelu_tanh(float x) {
  float u = 0.7978845608028654f * (x + 0.044715f * x * x * x);
  float e = __expf(2.0f * u);
  return 0.5f * x * (1.0f + (1.0f - 2.0f / (e + 1.0f)));
}
__device__ __forceinline__ void gll16(const void* gptr, void* lptr) {
  void* g = const_cast<void*>(gptr);
  __builtin_amdgcn_global_load_lds((__attribute__((address_space(1))) void*)g,
                                   (__attribute__((address_space(3))) void*)lptr,
                                   16, 0, 0);
}

// ---------------- h -> bf16 ----------------
__global__ void k_cvt_h(const float* __restrict__ h, ushort_t* __restrict__ hb) {
  int i = (blockIdx.x * 256 + threadIdx.x) * 8;
  float4 a = *(const float4*)(h + i);
  float4 b = *(const float4*)(h + i + 4);
  short8 v;
  v[0] = (short)f2bf(a.x); v[1] = (short)f2bf(a.y);
  v[2] = (short)f2bf(a.z); v[3] = (short)f2bf(a.w);
  v[4] = (short)f2bf(b.x); v[5] = (short)f2bf(b.y);
  v[6] = (short)f2bf(b.z); v[7] = (short)f2bf(b.w);
  *(short8*)(hb + i) = v;
}

// ---- transpose + cvt: in [E][R][C] f32 -> out [E][C][R] bf16, LDS-tiled ----
__global__ void k_transpose_bf16(const float* __restrict__ in, ushort_t* __restrict__ out,
                                 int R, int C) {
  __shared__ float ltf[64][65];
  const size_t per = (size_t)R * C;
  const float* src = in + per * blockIdx.z;
  ushort_t* dst = out + per * blockIdx.z;
  int r0 = blockIdx.x * 64, c0 = blockIdx.y * 64;
  int tid = threadIdx.x;
  int cg = (tid & 15) * 4;
  int rr = tid >> 4;
#pragma unroll
  for (int rb = 0; rb < 64; rb += 16) {
    int r = rb + rr;
    float4 v = *(const float4*)(src + (size_t)(r0 + r) * C + c0 + cg);
    ltf[r][cg + 0] = v.x; ltf[r][cg + 1] = v.y;
    ltf[r][cg + 2] = v.z; ltf[r][cg + 3] = v.w;
  }
  __syncthreads();
  int c = tid >> 2, rch = (tid & 3) * 16;
  ushort_t tmp[16];
#pragma unroll
  for (int i = 0; i < 16; ++i) tmp[i] = f2bf(ltf[rch + i][c]);
  ushort_t* dp = dst + (size_t)(c0 + c) * R + r0 + rch;
  *(us8*)dp = *(const us8*)&tmp[0];
  *(us8*)(dp + 8) = *(const us8*)&tmp[8];
}

// ------- router layer1 split-K: p1[kc] = h[:, kc*256:+256] @ gw1 chunk, f64 --
__global__ void k_router1(const float* __restrict__ h, const float* __restrict__ gw1,
                          double* __restrict__ p1) {
  __shared__ float sA[16][65];
  __shared__ float sB[16][65];
  int tx = threadIdx.x, ty = threadIdx.y;
  int tid = ty * 16 + tx;
  int m0 = blockIdx.y * 64, n0 = blockIdx.x * 64;
  int kc = blockIdx.z;
  double acc[4][4] = {};
  for (int k0 = kc * 256; k0 < kc * 256 + 256; k0 += 16) {
    {
      int m = tid & 63, kq = tid >> 6;
      float4 v = *(const float4*)(h + (size_t)(m0 + m) * D_ + k0 + kq * 4);
      sA[kq*4+0][m] = v.x; sA[kq*4+1][m] = v.y; sA[kq*4+2][m] = v.z; sA[kq*4+3][m] = v.w;
    }
    {
      int k = tid >> 4, nq = tid & 15;
      float4 v = *(const float4*)(gw1 + (size_t)(k0 + k) * H1_ + n0 + nq * 4);
      sB[k][nq*4+0] = v.x; sB[k][nq*4+1] = v.y; sB[k][nq*4+2] = v.z; sB[k][nq*4+3] = v.w;
    }
    __syncthreads();
#pragma unroll
    for (int k = 0; k < 16; ++k) {
      float a[4], b[4];
#pragma unroll
      for (int i = 0; i < 4; ++i) a[i] = sA[k][ty + i * 16];
#pragma unroll
      for (int j = 0; j < 4; ++j) b[j] = sB[k][tx * 4 + j];
#pragma unroll
      for (int i = 0; i < 4; ++i)
#pragma unroll
        for (int j = 0; j < 4; ++j)
          acc[i][j] += (double)a[i] * (double)b[j];
    }
    __syncthreads();
  }
  double* pd = p1 + (size_t)kc * T_ * H1_;
  for (int i = 0; i < 4; ++i)
    for (int j = 0; j < 4; ++j) {
      int m = m0 + ty + i * 16, n = n0 + tx * 4 + j;
      pd[(size_t)m * H1_ + n] = acc[i][j];
    }
}

// -------- router: reduce p1 + layers 2+3 + top-2 + counts (wave per token) ---
__global__ void k_router23(const double* __restrict__ p1, const float* __restrict__ gb1,
                           const float* __restrict__ gw2, const float* __restrict__ gb2,
                           const float* __restrict__ gw3,
                           float* __restrict__ logits_out, int* __restrict__ tokExp,
                           float* __restrict__ tokW, int* __restrict__ counts) {
  __shared__ double sG1[4][256];
  __shared__ double sG2[4][64];
  __shared__ double sL[4][8];
  int lane = threadIdx.x & 63, wv = threadIdx.x >> 6;
  int t = blockIdx.x * 4 + wv;
  const size_t TH = (size_t)T_ * H1_;
  const double* gp = p1 + (size_t)t * H1_ + lane * 4;
  double s0 = 0, s1 = 0, s2 = 0, s3 = 0;
#pragma unroll
  for (int kc = 0; kc < 4; ++kc) {
    double2 va = *(const double2*)(gp + kc * TH);
    double2 vb = *(const double2*)(gp + kc * TH + 2);
    s0 += va.x; s1 += va.y; s2 += vb.x; s3 += vb.y;
  }
  int hbase = lane * 4;
  s0 += (double)gb1[hbase + 0]; s1 += (double)gb1[hbase + 1];
  s2 += (double)gb1[hbase + 2]; s3 += (double)gb1[hbase + 3];
  sG1[wv][hbase + 0] = s0 > 0.0 ? s0 : 0.0;
  sG1[wv][hbase + 1] = s1 > 0.0 ? s1 : 0.0;
  sG1[wv][hbase + 2] = s2 > 0.0 ? s2 : 0.0;
  sG1[wv][hbase + 3] = s3 > 0.0 ? s3 : 0.0;
  __syncthreads();
  double acc = (double)gb2[lane];
  for (int k = 0; k < H1_; ++k)
    acc += sG1[wv][k] * (double)gw2[k * H2_ + lane];
  sG2[wv][lane] = acc > 0.0 ? acc : 0.0;
  __syncthreads();
  if (lane < 8) {
    double l = 0.0;
    for (int j = 0; j < H2_; ++j) l += sG2[wv][j] * (double)gw3[j * E_ + lane];
    sL[wv][lane] = l;
    logits_out[(size_t)t * E_ + lane] = (float)l;
  }
  __syncthreads();
  if (lane == 0) {
    double best = -1e300, second = -1e300; int bi = 0, si = 0;
    for (int e = 0; e < E_; ++e) {
      double l = sL[wv][e];
      if (l > best)        { second = best; si = bi; best = l; bi = e; }
      else if (l > second) { second = l; si = e; }
    }
    double w0 = 1.0 / (1.0 + exp(second - best));
    tokExp[t*2]   = bi; tokExp[t*2+1] = si;
    tokW[t*2]     = (float)w0;
    tokW[t*2+1]   = (float)(1.0 - w0);
    atomicAdd(&counts[bi], 1);
    atomicAdd(&counts[si], 1);
  }
}

// ---- assign rows (local prefix of counts; global cursor atomics) ------------
__global__ void k_assign(const int* __restrict__ tokExp, const int* __restrict__ counts,
                         int* cursor, int* __restrict__ list, int* __restrict__ rowOf) {
  int t = blockIdx.x * 256 + threadIdx.x;
  int offs[E_];
  int s = 0;
#pragma unroll
  for (int e = 0; e < E_; ++e) { offs[e] = s; s += counts[e]; }
  for (int k = 0; k < 2; ++k) {
    int e = tokExp[t*2+k];
    int pos = atomicAdd(&cursor[e], 1);
    int row = offs[e] + pos;
    list[row] = t;
    rowOf[t*2+k] = row;
  }
}

// -------- grouped GEMM pass1: act = gelu(gather(h) @ w1t^T + b1) -------------
// 128x128 tile, BK=32, single-buffer m97 two-barrier structure (proven).
__global__ __launch_bounds__(256) void k_moe_ffn1(
    const ushort_t* __restrict__ hb, const ushort_t* __restrict__ w1t,
    const float* __restrict__ b1, ushort_t* __restrict__ act,
    const int* __restrict__ list, const int* __restrict__ counts) {
  int e = blockIdx.z;
  int off = 0;
  for (int ee = 0; ee < e; ++ee) off += counts[ee];
  int cnt = counts[e];
  int mt = blockIdx.y;
  if (mt * 128 >= cnt) return;
  int rowStart = off + mt * 128;
  int nBase = blockIdx.x * 128;
  const ushort_t* B = w1t + (size_t)e * F_ * D_;
  int tid = threadIdx.x, w = tid >> 6, lane = tid & 63;
  int m16 = lane & 15, kq = lane >> 4;
  __shared__ short8 lA[512];
  __shared__ short8 lB[512];
  int gr0 = rowStart + (w * 2) * 16 + m16;
  int gr1 = gr0 + 16;
  int t0 = list[min(gr0, NROW_ - 1)];
  int t1 = list[min(gr1, NROW_ - 1)];
  const ushort_t* aS0 = hb + (size_t)t0 * D_ + kq * 8;
  const ushort_t* aS1 = hb + (size_t)t1 * D_ + kq * 8;
  const ushort_t* bS0 = B + (size_t)(nBase + (w * 2) * 16 + m16) * D_ + kq * 8;
  const ushort_t* bS1 = bS0 + (size_t)16 * D_;
  short8* dA0 = &lA[(w * 2) * 64];
  short8* dA1 = &lA[(w * 2 + 1) * 64];
  short8* dB0 = &lB[(w * 2) * 64];
  short8* dB1 = &lB[(w * 2 + 1) * 64];
  int wr = w >> 1, wc = w & 1;
  f32x4 acc[4][4] = {};
  for (int k0 = 0; k0 < D_; k0 += 32) {
    gll16(aS0 + k0, dA0);
    gll16(aS1 + k0, dA1);
    gll16(bS0 + k0, dB0);
    gll16(bS1 + k0, dB1);
    __syncthreads();
    short8 af[4], bf4[4];
#pragma unroll
    for (int i = 0; i < 4; ++i) af[i] = lA[(wr * 4 + i) * 64 + lane];
#pragma unroll
    for (int j = 0; j < 4; ++j) bf4[j] = lB[(wc * 4 + j) * 64 + lane];
#pragma unroll
    for (int i = 0; i < 4; ++i)
#pragma unroll
      for (int j = 0; j < 4; ++j)
        acc[i][j] = __builtin_amdgcn_mfma_f32_16x16x32_bf16(af[i], bf4[j], acc[i][j], 0, 0, 0);
    __syncthreads();
  }
  const float* b1e = b1 + (size_t)e * F_;
  int quad = lane >> 4, cn = lane & 15;
#pragma unroll
  for (int i = 0; i < 4; ++i) {
    int lrow = (wr * 4 + i) * 16 + quad * 4;
#pragma unroll
    for (int r = 0; r < 4; ++r) {
      int slot = mt * 128 + lrow + r;
      if (slot < cnt) {
        size_t gr = (size_t)off + slot;
#pragma unroll
        for (int j = 0; j < 4; ++j) {
          int n = nBase + (wc * 4 + j) * 16 + cn;
          float x = acc[i][j][r] + b1e[n];
          act[gr * F_ + n] = f2bf(gelu_tanh(x));
        }
      }
    }
  }
}

// -------- grouped GEMM pass2 split-K=2: partial[kc] = act @ w2t^T ------------
// 128x128 tile, BK=32, m97 structure; K-range = kc*2048..+2048; f32 partials.
__global__ __launch_bounds__(256) void k_moe_ffn2(
    const ushort_t* __restrict__ act, const ushort_t* __restrict__ w2t,
    float* __restrict__ part, const int* __restrict__ counts) {
  int z = blockIdx.z;
  int e = z >> 1, kc = z & 1;
  int off = 0;
  for (int ee = 0; ee < e; ++ee) off += counts[ee];
  int cnt = counts[e];
  int mt = blockIdx.y;
  if (mt * 128 >= cnt) return;
  int rowStart = off + mt * 128;
  int nBase = blockIdx.x * 128;
  const ushort_t* B = w2t + (size_t)e * D_ * F_;
  int tid = threadIdx.x, w = tid >> 6, lane = tid & 63;
  int m16 = lane & 15, kq = lane >> 4;
  __shared__ short8 lA[512];
  __shared__ short8 lB[512];
  int gr0 = rowStart + (w * 2) * 16 + m16;
  int gr1 = gr0 + 16;
  const ushort_t* aS0 = act + (size_t)min(gr0, NROW_ - 1) * F_ + kq * 8;
  const ushort_t* aS1 = act + (size_t)min(gr1, NROW_ - 1) * F_ + kq * 8;
  const ushort_t* bS0 = B + (size_t)(nBase + (w * 2) * 16 + m16) * F_ + kq * 8;
  const ushort_t* bS1 = bS0 + (size_t)16 * F_;
  short8* dA0 = &lA[(w * 2) * 64];
  short8* dA1 = &lA[(w * 2 + 1) * 64];
  short8* dB0 = &lB[(w * 2) * 64];
  short8* dB1 = &lB[(w * 2 + 1) * 64];
  int wr = w >> 1, wc = w & 1;
  f32x4 acc[4][4] = {};
  int kBase = kc * (F_ / 2);
  for (int k0 = kBase; k0 < kBase + F_ / 2; k0 += 32) {
    gll16(aS0 + k0, dA0);
    gll16(aS1 + k0, dA1);
    gll16(bS0 + k0, dB0);
    gll16(bS1 + k0, dB1);
    __syncthreads();
    short8 af[4], bf4[4];
#pragma unroll
    for (int i = 0; i < 4; ++i) af[i] = lA[(wr * 4 + i) * 64 + lane];
#pragma unroll
    for (int j = 0; j < 4; ++j) bf4[j] = lB[(wc * 4 + j) * 64 + lane];
#pragma unroll
    for (int i = 0; i < 4; ++i)
#pragma unroll
      for (int j = 0; j < 4; ++j)
        acc[i][j] = __builtin_amdgcn_mfma_f32_16x16x32_bf16(af[i], bf4[j], acc[i][j], 0, 0, 0);
    __syncthreads();
  }
  float* pd = part + (size_t)kc * NROW_ * D_;
  int quad = lane >> 4, cn = lane & 15;
#pragma unroll
  for (int i = 0; i < 4; ++i) {
    int lrow = (wr * 4 + i) * 16 + quad * 4;
#pragma unroll
    for (int r = 0; r < 4; ++r) {
      int slot = mt * 128 + lrow + r;
      if (slot < cnt) {
        size_t gr = (size_t)off + slot;
#pragma unroll
        for (int j = 0; j < 4; ++j) {
          int n = nBase + (wc * 4 + j) * 16 + cn;
          pd[gr * D_ + n] = acc[i][j][r];
        }
      }
    }
  }
}

// -- combine: out[t] = sum_k tokW[t,k]*(part0[row_k]+part1[row_k]+b2[e_k]) ----
__global__ void k_combine(const float* __restrict__ part, const int* __restrict__ rowOf,
                          const int* __restrict__ tokExp, const float* __restrict__ tokW,
                          const float* __restrict__ b2, float* __restrict__ out) {
  int t = blockIdx.x;
  int rA = rowOf[t*2], rB = rowOf[t*2+1];
  int eA = tokExp[t*2], eB = tokExp[t*2+1];
  float wA = tokW[t*2] * SCALE_, wB = tokW[t*2+1] * SCALE_;
  int d = threadIdx.x * 4;
  const size_t P = (size_t)NROW_ * D_;
  float4 a0 = *(const float4*)(part + (size_t)rA * D_ + d);
  float4 a1 = *(const float4*)(part + P + (size_t)rA * D_ + d);
  float4 b0 = *(const float4*)(part + (size_t)rB * D_ + d);
  float4 b1 = *(const float4*)(part + P + (size_t)rB * D_ + d);
  float4 ba = *(const float4*)(b2 + (size_t)eA * D_ + d);
  float4 bb = *(const float4*)(b2 + (size_t)eB * D_ + d);
  float4 o;
  o.x = wA * (a0.x + a1.x + ba.x) + wB * (b0.x + b1.x + bb.x);
  o.y = wA * (a0.y + a1.y + ba.y) + wB * (b0.y + b1.y + bb.y);
  o.z = wA * (a0.z + a1.z + ba.z) + wB * (b0.z + b1.z + bb.z);
  o.w = wA * (a0.w + a1.w + ba.w) + wB * (b0.w + b1.w + bb.w);
  *(float4*)(out + (size_t)t * D_ + d) = o;
}

extern "C" void kernel_launch(void* const* d_in, const int* in_sizes, int n_in,
                              void* d_out, int out_size, void* d_ws, size_t ws_size,
                              hipStream_t stream) {
  const float* h   = (const float*)d_in[0];
  const float* gw1 = (const float*)d_in[1];
  const float* gb1 = (const float*)d_in[2];
  const float* gw2 = (const float*)d_in[3];
  const float* gb2 = (const float*)d_in[4];
  const float* gw3 = (const float*)d_in[5];
  const float* w1  = (const float*)d_in[6];
  const float* b1  = (const float*)d_in[7];
  const float* w2  = (const float*)d_in[8];
  const float* b2  = (const float*)d_in[9];
  float* out    = (float*)d_out;
  float* logits = out + (size_t)T_ * D_;

  char* ws = (char*)d_ws;
  size_t o = 0;
  auto alloc = [&](size_t bytes) -> void* {
    o = (o + 255) & ~(size_t)255;
    void* p = ws + o;
    o += bytes;
    return p;
  };
  int*      counts  = (int*)alloc(2 * E_ * 4);   // counts[8] + cursor[8], one memset
  int*      cursor  = counts + E_;
  int*      tokExp  = (int*)alloc((size_t)T_ * 2 * 4);
  float*    tokW    = (float*)alloc((size_t)T_ * 2 * 4);
  int*      list    = (int*)alloc((size_t)NROW_ * 4);
  int*      rowOf   = (int*)alloc((size_t)NROW_ * 4);
  ushort_t* hb      = (ushort_t*)alloc((size_t)T_ * D_ * 2);
  ushort_t* w2t     = (ushort_t*)alloc((size_t)E_ * D_ * F_ * 2);
  // act (64 MB) aliases p1 (32 MB; dead after k_router23)
  char*     bigA    = (char*)alloc((size_t)NROW_ * F_ * 2);
  double*   p1      = (double*)bigA;
  ushort_t* act     = (ushort_t*)bigA;
  // partial (2x NROW x D f32 = 64 MB) aliases w1t (64 MB; dead after ffn1)
  char*     bigB    = (char*)alloc((size_t)E_ * D_ * F_ * 2);
  ushort_t* w1t     = (ushort_t*)bigB;
  float*    part    = (float*)bigB;
  (void)ws_size; (void)in_sizes; (void)n_in; (void)out_size;

  hipMemsetAsync(counts, 0, 2 * E_ * 4, stream);
  k_cvt_h<<<T_ * D_ / 2048, 256, 0, stream>>>(h, hb);
  k_transpose_bf16<<<dim3(D_ / 64, F_ / 64, E_), 256, 0, stream>>>(w1, w1t, D_, F_);
  k_transpose_bf16<<<dim3(F_ / 64, D_ / 64, E_), 256, 0, stream>>>(w2, w2t, F_, D_);
  k_router1<<<dim3(H1_ / 64, T_ / 64, 4), dim3(16, 16), 0, stream>>>(h, gw1, p1);
  k_router23<<<T_ / 4, 256, 0, stream>>>(p1, gb1, gw2, gb2, gw3, logits, tokExp, tokW, counts);
  k_assign<<<T_ / 256, 256, 0, stream>>>(tokExp, counts, cursor, list, rowOf);
  k_moe_ffn1<<<dim3(F_ / 128, NROW_ / 128, E_), 256, 0, stream>>>(hb, w1t, b1, act, list, counts);
  k_moe_ffn2<<<dim3(D_ / 128, NROW_ / 128, E_ * 2), 256, 0, stream>>>(act, w2t, part, counts);
  k_combine<<<T_, 256, 0, stream>>>(part, rowOf, tokExp, tokW, b2, out);
}

// Round 4
// 930.745 us; speedup vs baseline: 1.0861x; 1.0037x over previous
//
#include <hip/hip_runtime.h>
#include <stdint.h>

#define T_  4096
#define D_  1024
#define E_  8
#define F_  4096
#define H1_ 256
#define H2_ 64
#define SCALE_ 1.0f
#define NROW_ (2 * T_)
#define NTILES_ 72   // max active 128-row m-tiles: 8192/128 + (E-1) = 71

typedef unsigned short ushort_t;
typedef unsigned int   uint32;
typedef __attribute__((ext_vector_type(8))) short  short8;
typedef __attribute__((ext_vector_type(4))) float  f32x4;
typedef __attribute__((ext_vector_type(8))) unsigned short us8;

__device__ __forceinline__ ushort_t f2bf(float f) {
  uint32 u = __float_as_uint(f);
  u += 0x7FFFu + ((u >> 16) & 1u);   // RNE
  return (ushort_t)(u >> 16);
}
// jax.nn.gelu default = tanh approximation
__device__ __forceinline__ float gelu_tanh(float x) {
  float u = 0.7978845608028654f * (x + 0.044715f * x * x * x);
  float e = __expf(2.0f * u);
  return 0.5f * x * (1.0f + (1.0f - 2.0f / (e + 1.0f)));
}
__device__ __forceinline__ void gll16(const void* gptr, void* lptr) {
  void* g = const_cast<void*>(gptr);
  __builtin_amdgcn_global_load_lds((__attribute__((address_space(1))) void*)g,
                                   (__attribute__((address_space(3))) void*)lptr,
                                   16, 0, 0);
}

// ---------------- h -> bf16 ----------------
__global__ void k_cvt_h(const float* __restrict__ h, ushort_t* __restrict__ hb) {
  int i = (blockIdx.x * 256 + threadIdx.x) * 8;
  float4 a = *(const float4*)(h + i);
  float4 b = *(const float4*)(h + i + 4);
  short8 v;
  v[0] = (short)f2bf(a.x); v[1] = (short)f2bf(a.y);
  v[2] = (short)f2bf(a.z); v[3] = (short)f2bf(a.w);
  v[4] = (short)f2bf(b.x); v[5] = (short)f2bf(b.y);
  v[6] = (short)f2bf(b.z); v[7] = (short)f2bf(b.w);
  *(short8*)(hb + i) = v;
}

// ---- transpose + cvt: in [E][R][C] f32 -> out [E][C][R] bf16, LDS-tiled ----
__global__ void k_transpose_bf16(const float* __restrict__ in, ushort_t* __restrict__ out,
                                 int R, int C) {
  __shared__ float ltf[64][65];
  const size_t per = (size_t)R * C;
  const float* src = in + per * blockIdx.z;
  ushort_t* dst = out + per * blockIdx.z;
  int r0 = blockIdx.x * 64, c0 = blockIdx.y * 64;
  int tid = threadIdx.x;
  int cg = (tid & 15) * 4;
  int rr = tid >> 4;
#pragma unroll
  for (int rb = 0; rb < 64; rb += 16) {
    int r = rb + rr;
    float4 v = *(const float4*)(src + (size_t)(r0 + r) * C + c0 + cg);
    ltf[r][cg + 0] = v.x; ltf[r][cg + 1] = v.y;
    ltf[r][cg + 2] = v.z; ltf[r][cg + 3] = v.w;
  }
  __syncthreads();
  int c = tid >> 2, rch = (tid & 3) * 16;
  ushort_t tmp[16];
#pragma unroll
  for (int i = 0; i < 16; ++i) tmp[i] = f2bf(ltf[rch + i][c]);
  ushort_t* dp = dst + (size_t)(c0 + c) * R + r0 + rch;
  *(us8*)dp = *(const us8*)&tmp[0];
  *(us8*)(dp + 8) = *(const us8*)&tmp[8];
}

// ------- router layer1 split-K: p1[kc] = h[:, kc*256:+256] @ gw1 chunk, f64 --
__global__ void k_router1(const float* __restrict__ h, const float* __restrict__ gw1,
                          double* __restrict__ p1) {
  __shared__ float sA[16][65];
  __shared__ float sB[16][65];
  int tx = threadIdx.x, ty = threadIdx.y;
  int tid = ty * 16 + tx;
  int m0 = blockIdx.y * 64, n0 = blockIdx.x * 64;
  int kc = blockIdx.z;
  double acc[4][4] = {};
  for (int k0 = kc * 256; k0 < kc * 256 + 256; k0 += 16) {
    {
      int m = tid & 63, kq = tid >> 6;
      float4 v = *(const float4*)(h + (size_t)(m0 + m) * D_ + k0 + kq * 4);
      sA[kq*4+0][m] = v.x; sA[kq*4+1][m] = v.y; sA[kq*4+2][m] = v.z; sA[kq*4+3][m] = v.w;
    }
    {
      int k = tid >> 4, nq = tid & 15;
      float4 v = *(const float4*)(gw1 + (size_t)(k0 + k) * H1_ + n0 + nq * 4);
      sB[k][nq*4+0] = v.x; sB[k][nq*4+1] = v.y; sB[k][nq*4+2] = v.z; sB[k][nq*4+3] = v.w;
    }
    __syncthreads();
#pragma unroll
    for (int k = 0; k < 16; ++k) {
      float a[4], b[4];
#pragma unroll
      for (int i = 0; i < 4; ++i) a[i] = sA[k][ty + i * 16];
#pragma unroll
      for (int j = 0; j < 4; ++j) b[j] = sB[k][tx * 4 + j];
#pragma unroll
      for (int i = 0; i < 4; ++i)
#pragma unroll
        for (int j = 0; j < 4; ++j)
          acc[i][j] += (double)a[i] * (double)b[j];
    }
    __syncthreads();
  }
  double* pd = p1 + (size_t)kc * T_ * H1_;
  for (int i = 0; i < 4; ++i)
    for (int j = 0; j < 4; ++j) {
      int m = m0 + ty + i * 16, n = n0 + tx * 4 + j;
      pd[(size_t)m * H1_ + n] = acc[i][j];
    }
}

// -------- router: reduce p1 + layers 2+3 + top-2 + counts (wave per token) ---
__global__ void k_router23(const double* __restrict__ p1, const float* __restrict__ gb1,
                           const float* __restrict__ gw2, const float* __restrict__ gb2,
                           const float* __restrict__ gw3,
                           float* __restrict__ logits_out, int* __restrict__ tokExp,
                           float* __restrict__ tokW, int* __restrict__ counts) {
  __shared__ double sG1[4][256];
  __shared__ double sG2[4][64];
  __shared__ double sL[4][8];
  int lane = threadIdx.x & 63, wv = threadIdx.x >> 6;
  int t = blockIdx.x * 4 + wv;
  const size_t TH = (size_t)T_ * H1_;
  const double* gp = p1 + (size_t)t * H1_ + lane * 4;
  double s0 = 0, s1 = 0, s2 = 0, s3 = 0;
#pragma unroll
  for (int kc = 0; kc < 4; ++kc) {
    double2 va = *(const double2*)(gp + kc * TH);
    double2 vb = *(const double2*)(gp + kc * TH + 2);
    s0 += va.x; s1 += va.y; s2 += vb.x; s3 += vb.y;
  }
  int hbase = lane * 4;
  s0 += (double)gb1[hbase + 0]; s1 += (double)gb1[hbase + 1];
  s2 += (double)gb1[hbase + 2]; s3 += (double)gb1[hbase + 3];
  sG1[wv][hbase + 0] = s0 > 0.0 ? s0 : 0.0;
  sG1[wv][hbase + 1] = s1 > 0.0 ? s1 : 0.0;
  sG1[wv][hbase + 2] = s2 > 0.0 ? s2 : 0.0;
  sG1[wv][hbase + 3] = s3 > 0.0 ? s3 : 0.0;
  __syncthreads();
  double acc = (double)gb2[lane];
  for (int k = 0; k < H1_; ++k)
    acc += sG1[wv][k] * (double)gw2[k * H2_ + lane];
  sG2[wv][lane] = acc > 0.0 ? acc : 0.0;
  __syncthreads();
  if (lane < 8) {
    double l = 0.0;
    for (int j = 0; j < H2_; ++j) l += sG2[wv][j] * (double)gw3[j * E_ + lane];
    sL[wv][lane] = l;
    logits_out[(size_t)t * E_ + lane] = (float)l;
  }
  __syncthreads();
  if (lane == 0) {
    double best = -1e300, second = -1e300; int bi = 0, si = 0;
    for (int e = 0; e < E_; ++e) {
      double l = sL[wv][e];
      if (l > best)        { second = best; si = bi; best = l; bi = e; }
      else if (l > second) { second = l; si = e; }
    }
    double w0 = 1.0 / (1.0 + exp(second - best));
    tokExp[t*2]   = bi; tokExp[t*2+1] = si;
    tokW[t*2]     = (float)w0;
    tokW[t*2+1]   = (float)(1.0 - w0);
    atomicAdd(&counts[bi], 1);
    atomicAdd(&counts[si], 1);
  }
}

// ---- assign rows + build m-tile table (tileE, tileRow, tileCnt) -------------
__global__ void k_assign(const int* __restrict__ tokExp, const int* __restrict__ counts,
                         int* cursor, int* __restrict__ list, int* __restrict__ rowOf,
                         int* __restrict__ tileTab) {
  int offs[E_];
  int s = 0;
#pragma unroll
  for (int e = 0; e < E_; ++e) { offs[e] = s; s += counts[e]; }
  if (blockIdx.x == 0 && threadIdx.x == 0) {
    // tileTab layout: [NTILES_][3] = {expert, absRowStart, rowsInTile}
    int nt = 0;
    for (int e = 0; e < E_; ++e) {
      int cnt = counts[e];
      for (int m = 0; m * 128 < cnt; ++m) {
        tileTab[nt*3+0] = e;
        tileTab[nt*3+1] = offs[e] + m * 128;
        tileTab[nt*3+2] = (cnt - m * 128) < 128 ? (cnt - m * 128) : 128;
        ++nt;
      }
    }
    for (; nt < NTILES_; ++nt) tileTab[nt*3+0] = -1;
  }
  int t = blockIdx.x * 256 + threadIdx.x;
  for (int k = 0; k < 2; ++k) {
    int e = tokExp[t*2+k];
    int pos = atomicAdd(&cursor[e], 1);
    int row = offs[e] + pos;
    list[row] = t;
    rowOf[t*2+k] = row;
  }
}

// -------- grouped GEMM pass1: act = gelu(gather(h) @ w1t^T + b1) -------------
// 128x128 tile, BK=32, m97 two-barrier structure; tile-table dispatch.
__global__ __launch_bounds__(256) void k_moe_ffn1(
    const ushort_t* __restrict__ hb, const ushort_t* __restrict__ w1t,
    const float* __restrict__ b1, ushort_t* __restrict__ act,
    const int* __restrict__ list, const int* __restrict__ tileTab) {
  int ti = blockIdx.y;
  int e = tileTab[ti*3+0];
  if (e < 0) return;
  int rowStart = tileTab[ti*3+1];
  int cntTile  = tileTab[ti*3+2];
  int nBase = blockIdx.x * 128;
  const ushort_t* B = w1t + (size_t)e * F_ * D_;
  int tid = threadIdx.x, w = tid >> 6, lane = tid & 63;
  int m16 = lane & 15, kq = lane >> 4;
  __shared__ short8 lA[512];
  __shared__ short8 lB[512];
  int gr0 = rowStart + (w * 2) * 16 + m16;
  int gr1 = gr0 + 16;
  int t0 = list[min(gr0, NROW_ - 1)];
  int t1 = list[min(gr1, NROW_ - 1)];
  const ushort_t* aS0 = hb + (size_t)t0 * D_ + kq * 8;
  const ushort_t* aS1 = hb + (size_t)t1 * D_ + kq * 8;
  const ushort_t* bS0 = B + (size_t)(nBase + (w * 2) * 16 + m16) * D_ + kq * 8;
  const ushort_t* bS1 = bS0 + (size_t)16 * D_;
  short8* dA0 = &lA[(w * 2) * 64];
  short8* dA1 = &lA[(w * 2 + 1) * 64];
  short8* dB0 = &lB[(w * 2) * 64];
  short8* dB1 = &lB[(w * 2 + 1) * 64];
  int wr = w >> 1, wc = w & 1;
  f32x4 acc[4][4] = {};
  for (int k0 = 0; k0 < D_; k0 += 32) {
    gll16(aS0 + k0, dA0);
    gll16(aS1 + k0, dA1);
    gll16(bS0 + k0, dB0);
    gll16(bS1 + k0, dB1);
    __syncthreads();
    short8 af[4], bf4[4];
#pragma unroll
    for (int i = 0; i < 4; ++i) af[i] = lA[(wr * 4 + i) * 64 + lane];
#pragma unroll
    for (int j = 0; j < 4; ++j) bf4[j] = lB[(wc * 4 + j) * 64 + lane];
#pragma unroll
    for (int i = 0; i < 4; ++i)
#pragma unroll
      for (int j = 0; j < 4; ++j)
        acc[i][j] = __builtin_amdgcn_mfma_f32_16x16x32_bf16(af[i], bf4[j], acc[i][j], 0, 0, 0);
    __syncthreads();
  }
  const float* b1e = b1 + (size_t)e * F_;
  int quad = lane >> 4, cn = lane & 15;
#pragma unroll
  for (int i = 0; i < 4; ++i) {
    int lrow = (wr * 4 + i) * 16 + quad * 4;
#pragma unroll
    for (int r = 0; r < 4; ++r) {
      if (lrow + r < cntTile) {
        size_t gr = (size_t)rowStart + lrow + r;
#pragma unroll
        for (int j = 0; j < 4; ++j) {
          int n = nBase + (wc * 4 + j) * 16 + cn;
          float x = acc[i][j][r] + b1e[n];
          act[gr * F_ + n] = f2bf(gelu_tanh(x));
        }
      }
    }
  }
}

// -------- grouped GEMM pass2 split-K=2: partial[kc] = act @ w2t^T ------------
__global__ __launch_bounds__(256) void k_moe_ffn2(
    const ushort_t* __restrict__ act, const ushort_t* __restrict__ w2t,
    float* __restrict__ part, const int* __restrict__ tileTab) {
  int ti = blockIdx.y;
  int e = tileTab[ti*3+0];
  if (e < 0) return;
  int rowStart = tileTab[ti*3+1];
  int cntTile  = tileTab[ti*3+2];
  int kc = blockIdx.z;
  int nBase = blockIdx.x * 128;
  const ushort_t* B = w2t + (size_t)e * D_ * F_;
  int tid = threadIdx.x, w = tid >> 6, lane = tid & 63;
  int m16 = lane & 15, kq = lane >> 4;
  __shared__ short8 lA[512];
  __shared__ short8 lB[512];
  int gr0 = rowStart + (w * 2) * 16 + m16;
  int gr1 = gr0 + 16;
  const ushort_t* aS0 = act + (size_t)min(gr0, NROW_ - 1) * F_ + kq * 8;
  const ushort_t* aS1 = act + (size_t)min(gr1, NROW_ - 1) * F_ + kq * 8;
  const ushort_t* bS0 = B + (size_t)(nBase + (w * 2) * 16 + m16) * F_ + kq * 8;
  const ushort_t* bS1 = bS0 + (size_t)16 * F_;
  short8* dA0 = &lA[(w * 2) * 64];
  short8* dA1 = &lA[(w * 2 + 1) * 64];
  short8* dB0 = &lB[(w * 2) * 64];
  short8* dB1 = &lB[(w * 2 + 1) * 64];
  int wr = w >> 1, wc = w & 1;
  f32x4 acc[4][4] = {};
  int kBase = kc * (F_ / 2);
  for (int k0 = kBase; k0 < kBase + F_ / 2; k0 += 32) {
    gll16(aS0 + k0, dA0);
    gll16(aS1 + k0, dA1);
    gll16(bS0 + k0, dB0);
    gll16(bS1 + k0, dB1);
    __syncthreads();
    short8 af[4], bf4[4];
#pragma unroll
    for (int i = 0; i < 4; ++i) af[i] = lA[(wr * 4 + i) * 64 + lane];
#pragma unroll
    for (int j = 0; j < 4; ++j) bf4[j] = lB[(wc * 4 + j) * 64 + lane];
#pragma unroll
    for (int i = 0; i < 4; ++i)
#pragma unroll
      for (int j = 0; j < 4; ++j)
        acc[i][j] = __builtin_amdgcn_mfma_f32_16x16x32_bf16(af[i], bf4[j], acc[i][j], 0, 0, 0);
    __syncthreads();
  }
  float* pd = part + (size_t)kc * NROW_ * D_;
  int quad = lane >> 4, cn = lane & 15;
#pragma unroll
  for (int i = 0; i < 4; ++i) {
    int lrow = (wr * 4 + i) * 16 + quad * 4;
#pragma unroll
    for (int r = 0; r < 4; ++r) {
      if (lrow + r < cntTile) {
        size_t gr = (size_t)rowStart + lrow + r;
#pragma unroll
        for (int j = 0; j < 4; ++j) {
          int n = nBase + (wc * 4 + j) * 16 + cn;
          pd[gr * D_ + n] = acc[i][j][r];
        }
      }
    }
  }
}

// -- combine: out[t] = sum_k tokW[t,k]*(part0[row_k]+part1[row_k]+b2[e_k]) ----
__global__ void k_combine(const float* __restrict__ part, const int* __restrict__ rowOf,
                          const int* __restrict__ tokExp, const float* __restrict__ tokW,
                          const float* __restrict__ b2, float* __restrict__ out) {
  int t = blockIdx.x;
  int rA = rowOf[t*2], rB = rowOf[t*2+1];
  int eA = tokExp[t*2], eB = tokExp[t*2+1];
  float wA = tokW[t*2] * SCALE_, wB = tokW[t*2+1] * SCALE_;
  int d = threadIdx.x * 4;
  const size_t P = (size_t)NROW_ * D_;
  float4 a0 = *(const float4*)(part + (size_t)rA * D_ + d);
  float4 a1 = *(const float4*)(part + P + (size_t)rA * D_ + d);
  float4 b0 = *(const float4*)(part + (size_t)rB * D_ + d);
  float4 b1 = *(const float4*)(part + P + (size_t)rB * D_ + d);
  float4 ba = *(const float4*)(b2 + (size_t)eA * D_ + d);
  float4 bb = *(const float4*)(b2 + (size_t)eB * D_ + d);
  float4 o;
  o.x = wA * (a0.x + a1.x + ba.x) + wB * (b0.x + b1.x + bb.x);
  o.y = wA * (a0.y + a1.y + ba.y) + wB * (b0.y + b1.y + bb.y);
  o.z = wA * (a0.z + a1.z + ba.z) + wB * (b0.z + b1.z + bb.z);
  o.w = wA * (a0.w + a1.w + ba.w) + wB * (b0.w + b1.w + bb.w);
  *(float4*)(out + (size_t)t * D_ + d) = o;
}

extern "C" void kernel_launch(void* const* d_in, const int* in_sizes, int n_in,
                              void* d_out, int out_size, void* d_ws, size_t ws_size,
                              hipStream_t stream) {
  const float* h   = (const float*)d_in[0];
  const float* gw1 = (const float*)d_in[1];
  const float* gb1 = (const float*)d_in[2];
  const float* gw2 = (const float*)d_in[3];
  const float* gb2 = (const float*)d_in[4];
  const float* gw3 = (const float*)d_in[5];
  const float* w1  = (const float*)d_in[6];
  const float* b1  = (const float*)d_in[7];
  const float* w2  = (const float*)d_in[8];
  const float* b2  = (const float*)d_in[9];
  float* out    = (float*)d_out;
  float* logits = out + (size_t)T_ * D_;

  char* ws = (char*)d_ws;
  size_t o = 0;
  auto alloc = [&](size_t bytes) -> void* {
    o = (o + 255) & ~(size_t)255;
    void* p = ws + o;
    o += bytes;
    return p;
  };
  int*      counts  = (int*)alloc(2 * E_ * 4);   // counts[8] + cursor[8], one memset
  int*      cursor  = counts + E_;
  int*      tileTab = (int*)alloc((size_t)NTILES_ * 3 * 4);
  int*      tokExp  = (int*)alloc((size_t)T_ * 2 * 4);
  float*    tokW    = (float*)alloc((size_t)T_ * 2 * 4);
  int*      list    = (int*)alloc((size_t)NROW_ * 4);
  int*      rowOf   = (int*)alloc((size_t)NROW_ * 4);
  ushort_t* hb      = (ushort_t*)alloc((size_t)T_ * D_ * 2);
  ushort_t* w2t     = (ushort_t*)alloc((size_t)E_ * D_ * F_ * 2);
  // act (64 MB) aliases p1 (32 MB; dead after k_router23)
  char*     bigA    = (char*)alloc((size_t)NROW_ * F_ * 2);
  double*   p1      = (double*)bigA;
  ushort_t* act     = (ushort_t*)bigA;
  // partial (2x NROW x D f32 = 64 MB) aliases w1t (64 MB; dead after ffn1)
  char*     bigB    = (char*)alloc((size_t)E_ * D_ * F_ * 2);
  ushort_t* w1t     = (ushort_t*)bigB;
  float*    part    = (float*)bigB;
  (void)ws_size; (void)in_sizes; (void)n_in; (void)out_size;

  hipMemsetAsync(counts, 0, 2 * E_ * 4, stream);
  k_cvt_h<<<T_ * D_ / 2048, 256, 0, stream>>>(h, hb);
  k_transpose_bf16<<<dim3(D_ / 64, F_ / 64, E_), 256, 0, stream>>>(w1, w1t, D_, F_);
  k_transpose_bf16<<<dim3(F_ / 64, D_ / 64, E_), 256, 0, stream>>>(w2, w2t, F_, D_);
  k_router1<<<dim3(H1_ / 64, T_ / 64, 4), dim3(16, 16), 0, stream>>>(h, gw1, p1);
  k_router23<<<T_ / 4, 256, 0, stream>>>(p1, gb1, gw2, gb2, gw3, logits, tokExp, tokW, counts);
  k_assign<<<T_ / 256, 256, 0, stream>>>(tokExp, counts, cursor, list, rowOf, tileTab);
  k_moe_ffn1<<<dim3(F_ / 128, NTILES_), 256, 0, stream>>>(hb, w1t, b1, act, list, tileTab);
  k_moe_ffn2<<<dim3(D_ / 128, NTILES_, 2), 256, 0, stream>>>(act, w2t, part, tileTab);
  k_combine<<<T_, 256, 0, stream>>>(part, rowOf, tokExp, tokW, b2, out);
}